// Round 2
// baseline (54.920 us; speedup 1.0000x reference)
//
#include <hip/hip_runtime.h>
#include <hip/hip_bf16.h>
#include <stdint.h>

// Problem geometry
#define NB 64          // batch
#define NC 64          // C_IN
#define NU 2048        // N_UNITS
#define K_REAL 1296    // H*W = 36*36
#define K_PAD  1344    // 2*672 = 2*21*32, zero-padded K (split-K friendly)
#define M_ROWS 4096    // NB*NC

// GEMM tile
#define BM 128
#define BN 128
#define BK 32
#define K_SPLIT 672    // per-split K extent
#define NKT_S (K_SPLIT / BK)   // 21 K-steps per split

typedef __attribute__((ext_vector_type(4))) float f32x4;
typedef __attribute__((ext_vector_type(8))) short bf16x8;

__device__ __forceinline__ unsigned short f2bf_rne(float f) {
  union { float f; uint32_t u; } v; v.f = f;
  uint32_t u = v.u;
  return (unsigned short)((u + 0x7FFFu + ((u >> 16) & 1u)) >> 16);
}

// Convert fp32 [rows][K_REAL] -> bf16 [rows][K_PAD], zero-filling the pad
// tail. Handles BOTH x (rows 0..4095) and sw (rows 4096..6143) in one launch.
__global__ void convert_pad_kernel(const float* __restrict__ x,
                                   const float* __restrict__ sw,
                                   unsigned short* __restrict__ dst) {
  const int KB = K_PAD / 8;  // 168 8-element blocks per row
  const int total = (M_ROWS + NU) * KB;
  for (int idx = blockIdx.x * blockDim.x + threadIdx.x; idx < total;
       idx += gridDim.x * blockDim.x) {
    int r  = idx / KB;
    int kb = idx - r * KB;
    int k0 = kb * 8;
    uint32_t p0 = 0, p1 = 0, p2 = 0, p3 = 0;
    if (k0 + 8 <= K_REAL) {  // K_REAL % 8 == 0: blocks are all-real or all-pad
      const float* srow = (r < M_ROWS) ? (x + (size_t)r * K_REAL)
                                       : (sw + (size_t)(r - M_ROWS) * K_REAL);
      const float4* s = (const float4*)(srow + k0);
      float4 f0 = s[0];
      float4 f1 = s[1];
      p0 = (uint32_t)f2bf_rne(f0.x) | ((uint32_t)f2bf_rne(f0.y) << 16);
      p1 = (uint32_t)f2bf_rne(f0.z) | ((uint32_t)f2bf_rne(f0.w) << 16);
      p2 = (uint32_t)f2bf_rne(f1.x) | ((uint32_t)f2bf_rne(f1.y) << 16);
      p3 = (uint32_t)f2bf_rne(f1.z) | ((uint32_t)f2bf_rne(f1.w) << 16);
    }
    uint4 o; o.x = p0; o.y = p1; o.z = p2; o.w = p3;
    *(uint4*)(dst + (size_t)r * K_PAD + k0) = o;
  }
}

// Fused split-K GEMM: G[(b,c),u] = sum_hw xbf[(b,c),hw] * swbf[u,hw]
// epilogue: out[b,u] += sum_c fw[u,c]*G_partial[(b,c),u] (+ bias on split 0)
// M-tile of 128 rows = 2 complete batches -> per-wave epilogue reduction.
// LDS chunk swizzle: LDS slot (row, kc) holds global chunk kc ^ ((row>>1)&3)
// so consecutive-8-lane ds_read_b128 groups hit all 8 bank-quads.
__global__ __launch_bounds__(256)
void fused_readout_gemm(const unsigned short* __restrict__ Abf,  // [M_ROWS][K_PAD]
                        const unsigned short* __restrict__ Bbf,  // [NU][K_PAD]
                        const float* __restrict__ fw,            // [NU][NC]
                        const float* __restrict__ bias,          // [NU]
                        float* __restrict__ out) {               // [NB][NU]
  __shared__ unsigned short As[BM * BK];
  __shared__ unsigned short Bs[BN * BK];

  const int tid  = threadIdx.x;
  const int lane = tid & 63;
  const int w    = tid >> 6;
  const int wr   = w >> 1;      // 0..1: which 64-row half (which batch)
  const int wc   = w & 1;       // 0..1: which 64-col half
  const int g    = lane >> 4;   // k-group 0..3
  const int rl   = lane & 15;

  const int bid   = (int)blockIdx.x;
  const int split = bid >> 9;               // 0..1
  const int tileM = (bid >> 4) & 31;        // 0..31
  const int tileN = bid & 15;               // 0..15
  const int rowA0 = tileM * BM;
  const int colB0 = tileN * BN;
  const int kbase = split * K_SPLIT;

  f32x4 acc[4][4];
#pragma unroll
  for (int m = 0; m < 4; ++m)
#pragma unroll
    for (int n = 0; n < 4; ++n) acc[m][n] = (f32x4)0.f;

  const int swz_rd = (g ^ ((rl >> 1) & 3)) * 8;  // swizzled chunk offset (shorts)

  for (int kt = 0; kt < NKT_S; ++kt) {
    const int k0 = kbase + kt * BK;
    // Stage A and B tiles: 8KB each = 512 chunks of 16B; 256 threads x 2.
#pragma unroll
    for (int i = 0; i < 2; ++i) {
      const int ci  = i * 256 + tid;
      const int row = ci >> 2;                    // 0..127
      const int kc  = ci & 3;                     // LDS chunk slot
      const int kcg = kc ^ ((row >> 1) & 3);      // global chunk it holds
      const unsigned short* ga = Abf + (size_t)(rowA0 + row) * K_PAD + k0 + kcg * 8;
      __builtin_amdgcn_global_load_lds(
          (const __attribute__((address_space(1))) unsigned int*)(const void*)ga,
          (__attribute__((address_space(3))) unsigned int*)(void*)(As + ci * 8),
          16, 0, 0);
      const unsigned short* gb = Bbf + (size_t)(colB0 + row) * K_PAD + k0 + kcg * 8;
      __builtin_amdgcn_global_load_lds(
          (const __attribute__((address_space(1))) unsigned int*)(const void*)gb,
          (__attribute__((address_space(3))) unsigned int*)(void*)(Bs + ci * 8),
          16, 0, 0);
    }
    __syncthreads();

    bf16x8 a[4], b[4];
#pragma unroll
    for (int m = 0; m < 4; ++m)
      a[m] = *(const bf16x8*)(As + (wr * 64 + m * 16 + rl) * BK + swz_rd);
#pragma unroll
    for (int n = 0; n < 4; ++n)
      b[n] = *(const bf16x8*)(Bs + (wc * 64 + n * 16 + rl) * BK + swz_rd);
#pragma unroll
    for (int m = 0; m < 4; ++m)
#pragma unroll
      for (int n = 0; n < 4; ++n)
        acc[m][n] = __builtin_amdgcn_mfma_f32_16x16x32_bf16(a[m], b[n], acc[m][n], 0, 0, 0);
    __syncthreads();
  }

  // Epilogue: weighted reduction over the wave's 64 rows (= c of one batch).
  // acc[m][n] element j is G at c = m*16 + g*4 + j, u = colB0 + wc*64 + n*16 + rl.
  const int bidx = tileM * 2 + wr;
  float vtmp[4];
#pragma unroll
  for (int n = 0; n < 4; ++n) {
    const int u = colB0 + wc * 64 + n * 16 + rl;
    const float* fwrow = fw + (size_t)u * NC;
    float s = 0.f;
#pragma unroll
    for (int m = 0; m < 4; ++m) {
      float4 w4 = *(const float4*)(fwrow + m * 16 + g * 4);
      f32x4 av = acc[m][n];
      s += w4.x * av[0] + w4.y * av[1] + w4.z * av[2] + w4.w * av[3];
    }
    // reduce across the 4 k-groups (lanes xor 16, 32): lanes sharing (lane&15)
    s += __shfl_xor(s, 16, 64);
    s += __shfl_xor(s, 32, 64);
    vtmp[n] = s;
  }

  // Lane l handles u = colB0 + wc*64 + l, value from n = l>>4 (static select).
  const int ucol = colB0 + wc * 64 + lane;
  float r = (g == 0) ? vtmp[0] : (g == 1) ? vtmp[1] : (g == 2) ? vtmp[2] : vtmp[3];
  if (split == 0) r += bias[ucol];
  atomicAdd(&out[(size_t)bidx * NU + ucol], r);
}

extern "C" void kernel_launch(void* const* d_in, const int* in_sizes, int n_in,
                              void* d_out, int out_size, void* d_ws, size_t ws_size,
                              hipStream_t stream) {
  const float* x    = (const float*)d_in[0];  // [64,64,36,36] = [4096][1296]
  const float* fw   = (const float*)d_in[1];  // [2048,64,1,1]
  const float* bias = (const float*)d_in[2];  // [2048]
  const float* sw   = (const float*)d_in[3];  // [2048,36,36] = [2048][1296]
  float* out = (float*)d_out;                 // [64][2048]

  unsigned short* Abf = (unsigned short*)d_ws;            // 4096*1344*2 B
  unsigned short* Bbf = Abf + (size_t)M_ROWS * K_PAD;     // 2048*1344*2 B

  // Zero output (split-K accumulates with atomics)
  hipMemsetAsync(d_out, 0, (size_t)out_size * sizeof(float), stream);

  // Convert + zero-pad both inputs to bf16 (K-major for gemm_bt), one launch
  {
    int total = (M_ROWS + NU) * (K_PAD / 8);
    int blocks = (total + 255) / 256;
    if (blocks > 2048) blocks = 2048;
    convert_pad_kernel<<<blocks, 256, 0, stream>>>(x, sw, Abf);
  }

  // Fused split-K GEMM + readout: 2 splits x 32 M-tiles x 16 N-tiles
  fused_readout_gemm<<<dim3(2 * 32 * 16), 256, 0, stream>>>(Abf, Bbf, fw, bias, out);
}

// Round 3
// 53.854 us; speedup vs baseline: 1.0198x; 1.0198x over previous
//
#include <hip/hip_runtime.h>
#include <hip/hip_bf16.h>
#include <stdint.h>

// Problem geometry
#define NB 64          // batch
#define NC 64          // C_IN
#define NU 2048        // N_UNITS
#define K_REAL 1296    // H*W = 36*36
#define K_PAD  1344    // 2*672 = 2*21*32, zero-padded K (split-K friendly)
#define M_ROWS 4096    // NB*NC

// GEMM tile
#define BM 128
#define BN 128
#define BK 32
#define K_SPLIT 672    // per-split K extent
#define NKT_S (K_SPLIT / BK)   // 21 K-steps per split

typedef __attribute__((ext_vector_type(4))) float f32x4;
typedef __attribute__((ext_vector_type(8))) short bf16x8;

__device__ __forceinline__ unsigned short f2bf_rne(float f) {
  union { float f; uint32_t u; } v; v.f = f;
  uint32_t u = v.u;
  return (unsigned short)((u + 0x7FFFu + ((u >> 16) & 1u)) >> 16);
}

// Convert fp32 [rows][K_REAL] -> bf16 [rows][K_PAD], zero-filling the pad
// tail. Handles BOTH x (rows 0..4095) and sw (rows 4096..6143) in one launch.
__global__ void convert_pad_kernel(const float* __restrict__ x,
                                   const float* __restrict__ sw,
                                   unsigned short* __restrict__ dst) {
  const int KB = K_PAD / 8;  // 168 8-element blocks per row
  const int total = (M_ROWS + NU) * KB;
  for (int idx = blockIdx.x * blockDim.x + threadIdx.x; idx < total;
       idx += gridDim.x * blockDim.x) {
    int r  = idx / KB;
    int kb = idx - r * KB;
    int k0 = kb * 8;
    uint32_t p0 = 0, p1 = 0, p2 = 0, p3 = 0;
    if (k0 + 8 <= K_REAL) {  // K_REAL % 8 == 0: blocks are all-real or all-pad
      const float* srow = (r < M_ROWS) ? (x + (size_t)r * K_REAL)
                                       : (sw + (size_t)(r - M_ROWS) * K_REAL);
      const float4* s = (const float4*)(srow + k0);
      float4 f0 = s[0];
      float4 f1 = s[1];
      p0 = (uint32_t)f2bf_rne(f0.x) | ((uint32_t)f2bf_rne(f0.y) << 16);
      p1 = (uint32_t)f2bf_rne(f0.z) | ((uint32_t)f2bf_rne(f0.w) << 16);
      p2 = (uint32_t)f2bf_rne(f1.x) | ((uint32_t)f2bf_rne(f1.y) << 16);
      p3 = (uint32_t)f2bf_rne(f1.z) | ((uint32_t)f2bf_rne(f1.w) << 16);
    }
    uint4 o; o.x = p0; o.y = p1; o.z = p2; o.w = p3;
    *(uint4*)(dst + (size_t)r * K_PAD + k0) = o;
  }
}

// Fused split-K GEMM: G[(b,c),u] = sum_hw xbf[(b,c),hw] * swbf[u,hw]
// epilogue: part[split][b][u] = sum_c fw[u,c]*G_partial[(b,c),u]
// M-tile of 128 rows = 2 complete batches -> per-wave epilogue reduction,
// plain stores (each (split,b,u) written by exactly one wave -> no atomics).
// Double-buffered LDS: stage tile t+1 while computing tile t; one
// __syncthreads per K-step (implicit vmcnt(0)+lgkmcnt(0) drain covers both
// "prefetch landed" and "reads of old buffer done").
__global__ __launch_bounds__(256)
void fused_readout_gemm(const unsigned short* __restrict__ Abf,  // [M_ROWS][K_PAD]
                        const unsigned short* __restrict__ Bbf,  // [NU][K_PAD]
                        const float* __restrict__ fw,            // [NU][NC]
                        float* __restrict__ part) {              // [2][NB][NU]
  __shared__ unsigned short As[2][BM * BK];
  __shared__ unsigned short Bs[2][BN * BK];

  const int tid  = threadIdx.x;
  const int lane = tid & 63;
  const int w    = tid >> 6;
  const int wr   = w >> 1;      // 0..1: which 64-row half (which batch)
  const int wc   = w & 1;       // 0..1: which 64-col half
  const int g    = lane >> 4;   // k-group 0..3
  const int rl   = lane & 15;

  const int bid   = (int)blockIdx.x;
  const int split = bid >> 9;               // 0..1
  const int tileM = (bid >> 4) & 31;        // 0..31
  const int tileN = bid & 15;               // 0..15
  const int rowA0 = tileM * BM;
  const int colB0 = tileN * BN;
  const int kbase = split * K_SPLIT;

  // Staging geometry (per tile): 512 chunks of 16B each for A and B;
  // 256 threads x 2 issues. LDS chunk swizzle: slot (row,kc) holds global
  // chunk kc ^ ((row>>1)&3).
  const int ci0  = tid;
  const int ci1  = 256 + tid;
  const int row0 = ci0 >> 2, kc0 = ci0 & 3;
  const int row1 = ci1 >> 2, kc1 = ci1 & 3;
  const int kcg0 = kc0 ^ ((row0 >> 1) & 3);
  const int kcg1 = kc1 ^ ((row1 >> 1) & 3);
  const unsigned short* gA0 = Abf + (size_t)(rowA0 + row0) * K_PAD + kbase + kcg0 * 8;
  const unsigned short* gA1 = Abf + (size_t)(rowA0 + row1) * K_PAD + kbase + kcg1 * 8;
  const unsigned short* gB0 = Bbf + (size_t)(colB0 + row0) * K_PAD + kbase + kcg0 * 8;
  const unsigned short* gB1 = Bbf + (size_t)(colB0 + row1) * K_PAD + kbase + kcg1 * 8;

#define STAGE(buf, kt)                                                         \
  do {                                                                         \
    const int _k = (kt) * BK;                                                  \
    __builtin_amdgcn_global_load_lds(                                          \
        (const __attribute__((address_space(1))) unsigned int*)(const void*)(gA0 + _k), \
        (__attribute__((address_space(3))) unsigned int*)(void*)(As[buf] + ci0 * 8),    \
        16, 0, 0);                                                             \
    __builtin_amdgcn_global_load_lds(                                          \
        (const __attribute__((address_space(1))) unsigned int*)(const void*)(gA1 + _k), \
        (__attribute__((address_space(3))) unsigned int*)(void*)(As[buf] + ci1 * 8),    \
        16, 0, 0);                                                             \
    __builtin_amdgcn_global_load_lds(                                          \
        (const __attribute__((address_space(1))) unsigned int*)(const void*)(gB0 + _k), \
        (__attribute__((address_space(3))) unsigned int*)(void*)(Bs[buf] + ci0 * 8),    \
        16, 0, 0);                                                             \
    __builtin_amdgcn_global_load_lds(                                          \
        (const __attribute__((address_space(1))) unsigned int*)(const void*)(gB1 + _k), \
        (__attribute__((address_space(3))) unsigned int*)(void*)(Bs[buf] + ci1 * 8),    \
        16, 0, 0);                                                             \
  } while (0)

  f32x4 acc[4][4];
#pragma unroll
  for (int m = 0; m < 4; ++m)
#pragma unroll
    for (int n = 0; n < 4; ++n) acc[m][n] = (f32x4)0.f;

  const int swz_rd = (g ^ ((rl >> 1) & 3)) * 8;  // swizzled chunk offset (shorts)
  const int arow = (wr * 64 + rl) * BK;          // + m*16*BK per fragment
  const int brow = (wc * 64 + rl) * BK;

  STAGE(0, 0);
  __syncthreads();   // drains vmcnt(0): tile 0 staged

  int cur = 0;
  for (int kt = 0; kt < NKT_S; ++kt) {
    if (kt + 1 < NKT_S) STAGE(cur ^ 1, kt + 1);   // prefetch next tile

    bf16x8 a[4], b[4];
#pragma unroll
    for (int m = 0; m < 4; ++m)
      a[m] = *(const bf16x8*)(As[cur] + arow + m * 16 * BK + swz_rd);
#pragma unroll
    for (int n = 0; n < 4; ++n)
      b[n] = *(const bf16x8*)(Bs[cur] + brow + n * 16 * BK + swz_rd);
#pragma unroll
    for (int m = 0; m < 4; ++m)
#pragma unroll
      for (int n = 0; n < 4; ++n)
        acc[m][n] = __builtin_amdgcn_mfma_f32_16x16x32_bf16(a[m], b[n], acc[m][n], 0, 0, 0);

    __syncthreads();  // implicit vmcnt(0)+lgkmcnt(0): prefetch landed, reads done
    cur ^= 1;
  }
#undef STAGE

  // Epilogue: weighted reduction over the wave's 64 rows (= c of one batch).
  // acc[m][n] element j is G at c = m*16 + g*4 + j, u = colB0 + wc*64 + n*16 + rl.
  const int bidx = tileM * 2 + wr;
  float vtmp[4];
#pragma unroll
  for (int n = 0; n < 4; ++n) {
    const int u = colB0 + wc * 64 + n * 16 + rl;
    const float* fwrow = fw + (size_t)u * NC;
    float s = 0.f;
#pragma unroll
    for (int m = 0; m < 4; ++m) {
      float4 w4 = *(const float4*)(fwrow + m * 16 + g * 4);
      f32x4 av = acc[m][n];
      s += w4.x * av[0] + w4.y * av[1] + w4.z * av[2] + w4.w * av[3];
    }
    // reduce across the 4 k-groups (lanes xor 16, 32): lanes sharing (lane&15)
    s += __shfl_xor(s, 16, 64);
    s += __shfl_xor(s, 32, 64);
    vtmp[n] = s;
  }

  // Lane l handles u = colB0 + wc*64 + l, value from n = l>>4 (static select).
  const int ucol = colB0 + wc * 64 + lane;
  float r = (g == 0) ? vtmp[0] : (g == 1) ? vtmp[1] : (g == 2) ? vtmp[2] : vtmp[3];
  part[((size_t)split * NB + bidx) * NU + ucol] = r;
}

// out[b,u] = part[0][b][u] + part[1][b][u] + bias[u]
__global__ __launch_bounds__(256)
void combine_kernel(const float* __restrict__ part,
                    const float* __restrict__ bias,
                    float* __restrict__ out) {
  int f = blockIdx.x * blockDim.x + threadIdx.x;  // float4 index, 0..32767
  const float4* p0 = (const float4*)part;
  const float4* p1 = (const float4*)(part + (size_t)NB * NU);
  const float4* bz = (const float4*)bias;
  float4 a = p0[f];
  float4 b = p1[f];
  float4 c = bz[f & 511];   // u4 = f % (NU/4)
  float4 o;
  o.x = a.x + b.x + c.x;
  o.y = a.y + b.y + c.y;
  o.z = a.z + b.z + c.z;
  o.w = a.w + b.w + c.w;
  ((float4*)out)[f] = o;
}

extern "C" void kernel_launch(void* const* d_in, const int* in_sizes, int n_in,
                              void* d_out, int out_size, void* d_ws, size_t ws_size,
                              hipStream_t stream) {
  const float* x    = (const float*)d_in[0];  // [64,64,36,36] = [4096][1296]
  const float* fw   = (const float*)d_in[1];  // [2048,64,1,1]
  const float* bias = (const float*)d_in[2];  // [2048]
  const float* sw   = (const float*)d_in[3];  // [2048,36,36] = [2048][1296]
  float* out = (float*)d_out;                 // [64][2048]

  unsigned short* Abf = (unsigned short*)d_ws;            // 4096*1344*2 B
  unsigned short* Bbf = Abf + (size_t)M_ROWS * K_PAD;     // 2048*1344*2 B
  float* part = (float*)(Bbf + (size_t)NU * K_PAD);       // 2*64*2048*4 B

  // Convert + zero-pad both inputs to bf16 (K-major for gemm_bt), one launch
  {
    int total = (M_ROWS + NU) * (K_PAD / 8);
    int blocks = (total + 255) / 256;
    if (blocks > 2048) blocks = 2048;
    convert_pad_kernel<<<blocks, 256, 0, stream>>>(x, sw, Abf);
  }

  // Fused split-K GEMM + readout: 2 splits x 32 M-tiles x 16 N-tiles
  fused_readout_gemm<<<dim3(2 * 32 * 16), 256, 0, stream>>>(Abf, Bbf, fw, part);

  // Cross-split combine + bias
  combine_kernel<<<dim3((NB * NU / 4) / 256), 256, 0, stream>>>(part, bias, out);
}

// Round 4
// 51.981 us; speedup vs baseline: 1.0565x; 1.0360x over previous
//
#include <hip/hip_runtime.h>
#include <hip/hip_bf16.h>
#include <stdint.h>

// Problem geometry
#define NB 64          // batch
#define NC 64          // C_IN
#define NU 2048        // N_UNITS
#define K_REAL 1296    // H*W = 36*36
#define K_PAD  1344    // 2*672 = 2*21*32, zero-padded K (split-K friendly)
#define M_ROWS 4096    // NB*NC

// GEMM tile
#define BM 128
#define BN 128
#define BK 32
#define K_SPLIT 672    // per-split K extent
#define NKT_S (K_SPLIT / BK)   // 21 K-steps per split

typedef __attribute__((ext_vector_type(4))) float f32x4;
typedef __attribute__((ext_vector_type(8))) short bf16x8;

__device__ __forceinline__ unsigned short f2bf_rne(float f) {
  union { float f; uint32_t u; } v; v.f = f;
  uint32_t u = v.u;
  return (unsigned short)((u + 0x7FFFu + ((u >> 16) & 1u)) >> 16);
}

// Convert fp32 [rows][K_REAL] -> bf16 [rows][K_PAD], zero-filling the pad
// tail. Handles BOTH x (rows 0..4095) and sw (rows 4096..6143) in one launch.
__global__ void convert_pad_kernel(const float* __restrict__ x,
                                   const float* __restrict__ sw,
                                   unsigned short* __restrict__ dst) {
  const int KB = K_PAD / 8;  // 168 8-element blocks per row
  const int total = (M_ROWS + NU) * KB;
  for (int idx = blockIdx.x * blockDim.x + threadIdx.x; idx < total;
       idx += gridDim.x * blockDim.x) {
    int r  = idx / KB;
    int kb = idx - r * KB;
    int k0 = kb * 8;
    uint32_t p0 = 0, p1 = 0, p2 = 0, p3 = 0;
    if (k0 + 8 <= K_REAL) {  // K_REAL % 8 == 0: blocks are all-real or all-pad
      const float* srow = (r < M_ROWS) ? (x + (size_t)r * K_REAL)
                                       : (sw + (size_t)(r - M_ROWS) * K_REAL);
      const float4* s = (const float4*)(srow + k0);
      float4 f0 = s[0];
      float4 f1 = s[1];
      p0 = (uint32_t)f2bf_rne(f0.x) | ((uint32_t)f2bf_rne(f0.y) << 16);
      p1 = (uint32_t)f2bf_rne(f0.z) | ((uint32_t)f2bf_rne(f0.w) << 16);
      p2 = (uint32_t)f2bf_rne(f1.x) | ((uint32_t)f2bf_rne(f1.y) << 16);
      p3 = (uint32_t)f2bf_rne(f1.z) | ((uint32_t)f2bf_rne(f1.w) << 16);
    }
    uint4 o; o.x = p0; o.y = p1; o.z = p2; o.w = p3;
    *(uint4*)(dst + (size_t)r * K_PAD + k0) = o;
  }
}

// Fused split-K GEMM: G[(b,c),u] = sum_hw xbf[(b,c),hw] * swbf[u,hw]
// epilogue: part[split][b][u] = sum_c fw[u,c]*G_partial[(b,c),u]
// Triple-buffered LDS with COUNTED vmcnt pipeline (no per-step vmem drain):
//   prologue: STAGE(t0), STAGE(t1)                       [8 loads in flight]
//   iter t:   s_waitcnt vmcnt(4)   -> tile t's 4 loads done, t+1's remain
//             s_barrier            -> all waves: t staged, buf[(t+2)%3] free
//             STAGE(t+2)           -> loads span the next barriers
//             ds_read + MFMA on buf[t%3]
// Safety: barrier is after the wait and before the stage, so when STAGE(t+2)
// overwrites buf[(t-1)%3], every wave has already retired its ds_reads of it
// (lgkmcnt enforced before the MFMAs that precede the barrier).
__global__ __launch_bounds__(256)
void fused_readout_gemm(const unsigned short* __restrict__ Abf,  // [M_ROWS][K_PAD]
                        const unsigned short* __restrict__ Bbf,  // [NU][K_PAD]
                        const float* __restrict__ fw,            // [NU][NC]
                        float* __restrict__ part) {              // [2][NB][NU]
  __shared__ unsigned short As[3][BM * BK];
  __shared__ unsigned short Bs[3][BN * BK];

  const int tid  = threadIdx.x;
  const int lane = tid & 63;
  const int w    = tid >> 6;
  const int wr   = w >> 1;      // 0..1: which 64-row half (which batch)
  const int wc   = w & 1;       // 0..1: which 64-col half
  const int g    = lane >> 4;   // k-group 0..3
  const int rl   = lane & 15;

  // XCD-aware swizzle: 1024 blocks = 8 chunks of 128; chunk c -> XCD c.
  // Each chunk spans 8 tileM x 16 tileN of one split: ~4.1 MB shared panels.
  const int braw  = (int)blockIdx.x;
  const int bid   = (braw & 7) * 128 + (braw >> 3);
  const int split = bid >> 9;               // 0..1
  const int tileM = (bid >> 4) & 31;        // 0..31
  const int tileN = bid & 15;               // 0..15
  const int rowA0 = tileM * BM;
  const int colB0 = tileN * BN;
  const int kbase = split * K_SPLIT;

  // Staging geometry (per tile): 512 chunks of 16B each for A and B;
  // 256 threads x 2 issues. LDS chunk swizzle: slot (row,kc) holds global
  // chunk kc ^ ((row>>1)&3).
  const int ci0  = tid;
  const int ci1  = 256 + tid;
  const int row0 = ci0 >> 2, kc0 = ci0 & 3;
  const int row1 = ci1 >> 2, kc1 = ci1 & 3;
  const int kcg0 = kc0 ^ ((row0 >> 1) & 3);
  const int kcg1 = kc1 ^ ((row1 >> 1) & 3);
  const unsigned short* gA0 = Abf + (size_t)(rowA0 + row0) * K_PAD + kbase + kcg0 * 8;
  const unsigned short* gA1 = Abf + (size_t)(rowA0 + row1) * K_PAD + kbase + kcg1 * 8;
  const unsigned short* gB0 = Bbf + (size_t)(colB0 + row0) * K_PAD + kbase + kcg0 * 8;
  const unsigned short* gB1 = Bbf + (size_t)(colB0 + row1) * K_PAD + kbase + kcg1 * 8;

#define STAGE(buf, kt)                                                         \
  do {                                                                         \
    const int _k = (kt) * BK;                                                  \
    __builtin_amdgcn_global_load_lds(                                          \
        (const __attribute__((address_space(1))) unsigned int*)(const void*)(gA0 + _k), \
        (__attribute__((address_space(3))) unsigned int*)(void*)(As[buf] + ci0 * 8),    \
        16, 0, 0);                                                             \
    __builtin_amdgcn_global_load_lds(                                          \
        (const __attribute__((address_space(1))) unsigned int*)(const void*)(gA1 + _k), \
        (__attribute__((address_space(3))) unsigned int*)(void*)(As[buf] + ci1 * 8),    \
        16, 0, 0);                                                             \
    __builtin_amdgcn_global_load_lds(                                          \
        (const __attribute__((address_space(1))) unsigned int*)(const void*)(gB0 + _k), \
        (__attribute__((address_space(3))) unsigned int*)(void*)(Bs[buf] + ci0 * 8),    \
        16, 0, 0);                                                             \
    __builtin_amdgcn_global_load_lds(                                          \
        (const __attribute__((address_space(1))) unsigned int*)(const void*)(gB1 + _k), \
        (__attribute__((address_space(3))) unsigned int*)(void*)(Bs[buf] + ci1 * 8),    \
        16, 0, 0);                                                             \
  } while (0)

  f32x4 acc[4][4];
#pragma unroll
  for (int m = 0; m < 4; ++m)
#pragma unroll
    for (int n = 0; n < 4; ++n) acc[m][n] = (f32x4)0.f;

  const int swz_rd = (g ^ ((rl >> 1) & 3)) * 8;  // swizzled chunk offset (shorts)
  const int arow = (wr * 64 + rl) * BK;          // + m*16*BK per fragment
  const int brow = (wc * 64 + rl) * BK;

#define COMPUTE(buf)                                                           \
  do {                                                                         \
    bf16x8 a[4], b[4];                                                         \
    _Pragma("unroll")                                                          \
    for (int m = 0; m < 4; ++m)                                                \
      a[m] = *(const bf16x8*)(As[buf] + arow + m * 16 * BK + swz_rd);          \
    _Pragma("unroll")                                                          \
    for (int n = 0; n < 4; ++n)                                                \
      b[n] = *(const bf16x8*)(Bs[buf] + brow + n * 16 * BK + swz_rd);          \
    __builtin_amdgcn_s_setprio(1);                                             \
    _Pragma("unroll")                                                          \
    for (int m = 0; m < 4; ++m)                                                \
      _Pragma("unroll")                                                        \
      for (int n = 0; n < 4; ++n)                                              \
        acc[m][n] = __builtin_amdgcn_mfma_f32_16x16x32_bf16(a[m], b[n],        \
                                                            acc[m][n], 0, 0, 0); \
    __builtin_amdgcn_s_setprio(0);                                             \
  } while (0)

  STAGE(0, 0);
  STAGE(1, 1);

  int cur = 0, nx2 = 2;   // buffer of tile t, buffer of tile t+2
#pragma unroll 1
  for (int t = 0; t < NKT_S - 1; ++t) {
    asm volatile("s_waitcnt vmcnt(4)" ::: "memory");  // tile t landed; t+1 in flight
    __builtin_amdgcn_s_barrier();
    __builtin_amdgcn_sched_barrier(0);
    if (t + 2 < NKT_S) STAGE(nx2, t + 2);
    COMPUTE(cur);
    cur = (cur == 2) ? 0 : cur + 1;
    nx2 = (nx2 == 2) ? 0 : nx2 + 1;
  }
  // peeled last tile: nothing newer outstanding -> full drain required
  asm volatile("s_waitcnt vmcnt(0)" ::: "memory");
  __builtin_amdgcn_s_barrier();
  __builtin_amdgcn_sched_barrier(0);
  COMPUTE(cur);
#undef COMPUTE
#undef STAGE

  // Epilogue: weighted reduction over the wave's 64 rows (= c of one batch).
  // acc[m][n] element j is G at c = m*16 + g*4 + j, u = colB0 + wc*64 + n*16 + rl.
  const int bidx = tileM * 2 + wr;
  float vtmp[4];
#pragma unroll
  for (int n = 0; n < 4; ++n) {
    const int u = colB0 + wc * 64 + n * 16 + rl;
    const float* fwrow = fw + (size_t)u * NC;
    float s = 0.f;
#pragma unroll
    for (int m = 0; m < 4; ++m) {
      float4 w4 = *(const float4*)(fwrow + m * 16 + g * 4);
      f32x4 av = acc[m][n];
      s += w4.x * av[0] + w4.y * av[1] + w4.z * av[2] + w4.w * av[3];
    }
    // reduce across the 4 k-groups (lanes xor 16, 32): lanes sharing (lane&15)
    s += __shfl_xor(s, 16, 64);
    s += __shfl_xor(s, 32, 64);
    vtmp[n] = s;
  }

  // Lane l handles u = colB0 + wc*64 + l, value from n = l>>4 (static select).
  const int ucol = colB0 + wc * 64 + lane;
  float r = (g == 0) ? vtmp[0] : (g == 1) ? vtmp[1] : (g == 2) ? vtmp[2] : vtmp[3];
  part[((size_t)split * NB + bidx) * NU + ucol] = r;
}

// out[b,u] = part[0][b][u] + part[1][b][u] + bias[u]
__global__ __launch_bounds__(256)
void combine_kernel(const float* __restrict__ part,
                    const float* __restrict__ bias,
                    float* __restrict__ out) {
  int f = blockIdx.x * blockDim.x + threadIdx.x;  // float4 index, 0..32767
  const float4* p0 = (const float4*)part;
  const float4* p1 = (const float4*)(part + (size_t)NB * NU);
  const float4* bz = (const float4*)bias;
  float4 a = p0[f];
  float4 b = p1[f];
  float4 c = bz[f & 511];   // u4 = f % (NU/4)
  float4 o;
  o.x = a.x + b.x + c.x;
  o.y = a.y + b.y + c.y;
  o.z = a.z + b.z + c.z;
  o.w = a.w + b.w + c.w;
  ((float4*)out)[f] = o;
}

extern "C" void kernel_launch(void* const* d_in, const int* in_sizes, int n_in,
                              void* d_out, int out_size, void* d_ws, size_t ws_size,
                              hipStream_t stream) {
  const float* x    = (const float*)d_in[0];  // [64,64,36,36] = [4096][1296]
  const float* fw   = (const float*)d_in[1];  // [2048,64,1,1]
  const float* bias = (const float*)d_in[2];  // [2048]
  const float* sw   = (const float*)d_in[3];  // [2048,36,36] = [2048][1296]
  float* out = (float*)d_out;                 // [64][2048]

  unsigned short* Abf = (unsigned short*)d_ws;            // 4096*1344*2 B
  unsigned short* Bbf = Abf + (size_t)M_ROWS * K_PAD;     // 2048*1344*2 B
  float* part = (float*)(Bbf + (size_t)NU * K_PAD);       // 2*64*2048*4 B

  // Convert + zero-pad both inputs to bf16 (K-major for gemm_bt), one launch
  {
    int total = (M_ROWS + NU) * (K_PAD / 8);
    int blocks = (total + 255) / 256;
    if (blocks > 2048) blocks = 2048;
    convert_pad_kernel<<<blocks, 256, 0, stream>>>(x, sw, Abf);
  }

  // Fused split-K GEMM + readout: 2 splits x 32 M-tiles x 16 N-tiles
  fused_readout_gemm<<<dim3(2 * 32 * 16), 256, 0, stream>>>(Abf, Bbf, fw, part);

  // Cross-split combine + bias
  combine_kernel<<<dim3((NB * NU / 4) / 256), 256, 0, stream>>>(part, bias, out);
}